// Round 2
// baseline (1022.136 us; speedup 1.0000x reference)
//
#include <hip/hip_runtime.h>
#include <hip/hip_bf16.h>
#include <math.h>

#define F 128

__device__ __forceinline__ float rl(float v, int k) {
    return __int_as_float(__builtin_amdgcn_readlane(__float_as_int(v), k));
}

// ---------------- utility ----------------

__global__ void zero_i32(int* __restrict__ p, int n) {
    int i = blockIdx.x * blockDim.x + threadIdx.x;
    if (i < n) p[i] = 0;
}

// ---------------- CSR build ----------------

__global__ void count_deg(const int* __restrict__ dst, int E, int N,
                          int* __restrict__ deg) {
    int i = blockIdx.x * blockDim.x + threadIdx.x;
    int total = E + N;
    if (i >= total) return;
    int d = (i < E) ? dst[i] : (i - E);   // self-loops appended
    atomicAdd(&deg[d], 1);
}

__global__ void compute_dinv(const int* __restrict__ deg, float* __restrict__ dinv, int N) {
    int i = blockIdx.x * blockDim.x + threadIdx.x;
    if (i >= N) return;
    int d = deg[i];
    dinv[i] = d > 0 ? rsqrtf((float)d) : 0.0f;
}

// block-level exclusive scan (1024/block) -> partial + block sums
__global__ __launch_bounds__(1024) void scan_block(const int* __restrict__ deg,
                                                   int* __restrict__ out,
                                                   int* __restrict__ bsums, int N) {
    __shared__ int tmp[1024];
    int t = threadIdx.x;
    int gid = blockIdx.x * 1024 + t;
    int v = (gid < N) ? deg[gid] : 0;
    tmp[t] = v;
    __syncthreads();
    for (int off = 1; off < 1024; off <<= 1) {
        int add = (t >= off) ? tmp[t - off] : 0;
        __syncthreads();
        tmp[t] += add;
        __syncthreads();
    }
    if (gid < N) out[gid] = tmp[t] - v;     // exclusive within block
    if (t == 1023) bsums[blockIdx.x] = tmp[t];
}

__global__ __launch_bounds__(128) void scan_sums(int* __restrict__ bsums, int nb) {
    __shared__ int tmp[128];
    int t = threadIdx.x;
    int v = (t < nb) ? bsums[t] : 0;
    tmp[t] = v;
    __syncthreads();
    for (int off = 1; off < 128; off <<= 1) {
        int add = (t >= off) ? tmp[t - off] : 0;
        __syncthreads();
        tmp[t] += add;
        __syncthreads();
    }
    if (t < nb) bsums[t] = tmp[t] - v;      // exclusive over blocks
}

__global__ __launch_bounds__(1024) void scan_add(int* __restrict__ rp,
                                                 const int* __restrict__ bsums,
                                                 int N, int total) {
    int t = threadIdx.x;
    int gid = blockIdx.x * 1024 + t;
    if (gid < N) rp[gid] += bsums[blockIdx.x];
    if (gid == 0) rp[N] = total;
}

__global__ void fill_csr(const int* __restrict__ src, const int* __restrict__ dst,
                         int E, int N, const int* __restrict__ rp,
                         int* __restrict__ fill, int* __restrict__ col) {
    int i = blockIdx.x * blockDim.x + threadIdx.x;
    int total = E + N;
    if (i >= total) return;
    int s, d;
    if (i < E) { s = src[i]; d = dst[i]; }
    else       { s = d = i - E; }
    int pos = rp[d] + atomicAdd(&fill[d], 1);
    col[pos] = s;
}

// ------- fused layer 1: xa = (A_hat x), then relu(xa@W1+b1)@W2 -> h2pre -------
// One wave handles 4 nodes. Lane holds x-features (2*lane, 2*lane+1).

__global__ __launch_bounds__(512) void fused1(
    const float* __restrict__ x, const int* __restrict__ rp, const int* __restrict__ col,
    const float* __restrict__ dinv, const float* __restrict__ b1,
    const float* __restrict__ W1, const float* __restrict__ W2,
    float* __restrict__ h2pre, int N)
{
    __shared__ float Wl[F * F];   // 64 KB
    for (int idx = threadIdx.x; idx < F * F / 4; idx += 512)
        ((float4*)Wl)[idx] = ((const float4*)W1)[idx];
    __syncthreads();

    int wave = threadIdx.x >> 6, lane = threadIdx.x & 63;
    int node0 = blockIdx.x * 32 + wave * 4;
    if (node0 >= N) return;

    float b1a = b1[lane], b1b = b1[64 + lane];
    float w2a = W2[lane], w2b = W2[64 + lane];

    // aggregate: a0[n] = xa[2*lane], a1[n] = xa[2*lane+1] for node node0+n
    float a0[4] = {0.f, 0.f, 0.f, 0.f}, a1[4] = {0.f, 0.f, 0.f, 0.f};
#pragma unroll
    for (int n = 0; n < 4; ++n) {
        int i = node0 + n;
        if (i < N) {
            float di = dinv[i];
            int beg = rp[i], end = rp[i + 1];
            float s0 = 0.f, s1 = 0.f;
            for (int e = beg; e < end; ++e) {
                int s = col[e];
                float nrm = dinv[s];
                float2 xv = ((const float2*)(x + (size_t)s * F))[lane];
                s0 += nrm * xv.x;
                s1 += nrm * xv.y;
            }
            a0[n] = s0 * di;
            a1[n] = s1 * di;
        }
    }

    // matvec: out[j] = sum_k xa[k] * W1[k][j]; lane computes j=lane and j=64+lane
    float o0[4] = {0.f, 0.f, 0.f, 0.f}, o1[4] = {0.f, 0.f, 0.f, 0.f};
#pragma unroll 8
    for (int kk = 0; kk < 64; ++kk) {
        float w00 = Wl[(2 * kk) * F + lane];
        float w01 = Wl[(2 * kk) * F + 64 + lane];
        float w10 = Wl[(2 * kk + 1) * F + lane];
        float w11 = Wl[(2 * kk + 1) * F + 64 + lane];
#pragma unroll
        for (int n = 0; n < 4; ++n) {
            float xk0 = rl(a0[n], kk);
            float xk1 = rl(a1[n], kk);
            o0[n] += xk0 * w00 + xk1 * w10;
            o1[n] += xk0 * w01 + xk1 * w11;
        }
    }

#pragma unroll
    for (int n = 0; n < 4; ++n) {
        int i = node0 + n;
        if (i < N) {
            float v0 = fmaxf(o0[n] + b1a, 0.f);
            float v1 = fmaxf(o1[n] + b1b, 0.f);
            float dot = v0 * w2a + v1 * w2b;
#pragma unroll
            for (int off = 32; off; off >>= 1) dot += __shfl_down(dot, off);
            if (lane == 0) h2pre[i] = dot;
        }
    }
}

// ------- layer 2 aggregation (out dim 1) -> h2[N] -------

__global__ void agg2(const float* __restrict__ h2pre, const int* __restrict__ rp,
                     const int* __restrict__ col, const float* __restrict__ dinv,
                     const float* __restrict__ b2, float* __restrict__ h2, int N) {
    int i = blockIdx.x * blockDim.x + threadIdx.x;
    if (i >= N) return;
    float di = dinv[i];
    float acc = 0.f;
    int beg = rp[i], end = rp[i + 1];
    for (int e = beg; e < end; ++e) {
        int s = col[e];
        acc += dinv[s] * h2pre[s];
    }
    h2[i] = acc * di + b2[0];
}

// ------- edge probabilities -------

__global__ void edge_probs(const int* __restrict__ src, const int* __restrict__ dst,
                           const float* __restrict__ h2, float* __restrict__ out, int E) {
    int e = blockIdx.x * blockDim.x + threadIdx.x;
    if (e >= E) return;
    float v = h2[src[e]] * h2[dst[e]];
    out[e] = 1.0f / (1.0f + expf(-v));
}

// ---------------- launch ----------------

extern "C" void kernel_launch(void* const* d_in, const int* in_sizes, int n_in,
                              void* d_out, int out_size, void* d_ws, size_t ws_size,
                              hipStream_t stream) {
    const float* x  = (const float*)d_in[0];
    const int*   ei = (const int*)d_in[1];       // int32! (JAX x64 disabled)
    const float* b1 = (const float*)d_in[3];
    const float* W1 = (const float*)d_in[2];
    const float* W2 = (const float*)d_in[4];
    const float* b2 = (const float*)d_in[5];
    float* out = (float*)d_out;

    int N = in_sizes[0] / F;
    int E = in_sizes[1] / 2;
    const int* src = ei;
    const int* dst = ei + E;
    int total = E + N;

    // workspace layout (~16 MB)
    char* ws = (char*)d_ws;
    size_t off = 0;
    auto alloc = [&](size_t bytes) -> void* {
        off = (off + 255) & ~(size_t)255;
        void* p = ws + off;
        off += bytes;
        return p;
    };
    int*   deg   = (int*)alloc((size_t)N * 4);
    float* dinv  = (float*)alloc((size_t)N * 4);
    int*   rp    = (int*)alloc((size_t)(N + 1) * 4);
    int*   fill  = (int*)alloc((size_t)N * 4);
    int*   bsums = (int*)alloc(128 * 4);
    int*   col   = (int*)alloc((size_t)total * 4);
    float* h2pre = (float*)alloc((size_t)N * 4);
    float* h2    = (float*)alloc((size_t)N * 4);
    (void)ws_size;

    int nb = (N + 1023) / 1024;

    zero_i32<<<(N + 255) / 256, 256, 0, stream>>>(deg, N);
    zero_i32<<<(N + 255) / 256, 256, 0, stream>>>(fill, N);
    count_deg<<<(total + 255) / 256, 256, 0, stream>>>(dst, E, N, deg);
    compute_dinv<<<(N + 255) / 256, 256, 0, stream>>>(deg, dinv, N);
    scan_block<<<nb, 1024, 0, stream>>>(deg, rp, bsums, N);
    scan_sums<<<1, 128, 0, stream>>>(bsums, nb);
    scan_add<<<nb, 1024, 0, stream>>>(rp, bsums, N, total);
    fill_csr<<<(total + 255) / 256, 256, 0, stream>>>(src, dst, E, N, rp, fill, col);
    fused1<<<(N + 31) / 32, 512, 0, stream>>>(x, rp, col, dinv, b1, W1, W2, h2pre, N);
    agg2<<<(N + 255) / 256, 256, 0, stream>>>(h2pre, rp, col, dinv, b2, h2, N);
    edge_probs<<<(E + 255) / 256, 256, 0, stream>>>(src, dst, h2, out, E);
}

// Round 3
// 670.391 us; speedup vs baseline: 1.5247x; 1.5247x over previous
//
#include <hip/hip_runtime.h>
#include <hip/hip_bf16.h>
#include <math.h>

#define F 128

__device__ __forceinline__ float rl(float v, int k) {
    return __int_as_float(__builtin_amdgcn_readlane(__float_as_int(v), k));
}
__device__ __forceinline__ int rfl(int v) {
    return __builtin_amdgcn_readfirstlane(v);
}
__device__ __forceinline__ unsigned short f2bf(float f) {
    __hip_bfloat16 h = __float2bfloat16(f);
    return *reinterpret_cast<unsigned short*>(&h);
}
__device__ __forceinline__ float bf2f(unsigned short u) {
    return __uint_as_float((unsigned)u << 16);
}

// ---------------- utility ----------------

__global__ void zero_i32(int* __restrict__ p, int n) {
    int i = blockIdx.x * blockDim.x + threadIdx.x;
    if (i < n) p[i] = 0;
}

// ---------------- CSR build ----------------

__global__ void count_deg(const int* __restrict__ dst, int E, int N,
                          int* __restrict__ deg) {
    int i = blockIdx.x * blockDim.x + threadIdx.x;
    int total = E + N;
    if (i >= total) return;
    int d = (i < E) ? dst[i] : (i - E);   // self-loops appended
    atomicAdd(&deg[d], 1);
}

__global__ void compute_dinv(const int* __restrict__ deg, float* __restrict__ dinv, int N) {
    int i = blockIdx.x * blockDim.x + threadIdx.x;
    if (i >= N) return;
    int d = deg[i];
    dinv[i] = d > 0 ? rsqrtf((float)d) : 0.0f;
}

__global__ __launch_bounds__(1024) void scan_block(const int* __restrict__ deg,
                                                   int* __restrict__ out,
                                                   int* __restrict__ bsums, int N) {
    __shared__ int tmp[1024];
    int t = threadIdx.x;
    int gid = blockIdx.x * 1024 + t;
    int v = (gid < N) ? deg[gid] : 0;
    tmp[t] = v;
    __syncthreads();
    for (int off = 1; off < 1024; off <<= 1) {
        int add = (t >= off) ? tmp[t - off] : 0;
        __syncthreads();
        tmp[t] += add;
        __syncthreads();
    }
    if (gid < N) out[gid] = tmp[t] - v;     // exclusive within block
    if (t == 1023) bsums[blockIdx.x] = tmp[t];
}

__global__ __launch_bounds__(128) void scan_sums(int* __restrict__ bsums, int nb) {
    __shared__ int tmp[128];
    int t = threadIdx.x;
    int v = (t < nb) ? bsums[t] : 0;
    tmp[t] = v;
    __syncthreads();
    for (int off = 1; off < 128; off <<= 1) {
        int add = (t >= off) ? tmp[t - off] : 0;
        __syncthreads();
        tmp[t] += add;
        __syncthreads();
    }
    if (t < nb) bsums[t] = tmp[t] - v;      // exclusive over blocks
}

__global__ __launch_bounds__(1024) void scan_add(int* __restrict__ rp,
                                                 const int* __restrict__ bsums,
                                                 int N, int total) {
    int t = threadIdx.x;
    int gid = blockIdx.x * 1024 + t;
    if (gid < N) rp[gid] += bsums[blockIdx.x];
    if (gid == 0) rp[N] = total;
}

__global__ void fill_csr(const int* __restrict__ src, const int* __restrict__ dst,
                         int E, int N, const int* __restrict__ rp,
                         int* __restrict__ fill, int* __restrict__ col) {
    int i = blockIdx.x * blockDim.x + threadIdx.x;
    int total = E + N;
    if (i >= total) return;
    int s, d;
    if (i < E) { s = src[i]; d = dst[i]; }
    else       { s = d = i - E; }
    int pos = rp[d] + atomicAdd(&fill[d], 1);
    col[pos] = s;
}

// ------- prescale: xs[n][f] = bf16(dinv[n] * x[n][f]) -------

__global__ void prescale(const float* __restrict__ x, const float* __restrict__ dinv,
                         unsigned short* __restrict__ xs, int N) {
    int i = blockIdx.x * blockDim.x + threadIdx.x;   // float4 group index
    int ngroups = N * (F / 4);
    if (i >= ngroups) return;
    int row = i >> 5;                                 // /(F/4)
    float d = dinv[row];
    float4 v = ((const float4*)x)[i];
    ushort4 o;
    o.x = f2bf(v.x * d); o.y = f2bf(v.y * d);
    o.z = f2bf(v.z * d); o.w = f2bf(v.w * d);
    ((ushort4*)xs)[i] = o;
}

// ------- fused layer 1: xa = dinv_i * sum(xs[neigh]); h2s = dinv_i*(relu(xa@W1+b1)@W2) -------
// Wave handles 4 nodes, interleaved edge loops, 2 neighbor rows per gather instr.

__global__ __launch_bounds__(512, 6) void fused1(
    const unsigned short* __restrict__ xs, const int* __restrict__ rp,
    const int* __restrict__ col, const float* __restrict__ dinv,
    const float* __restrict__ b1, const float* __restrict__ W1,
    const float* __restrict__ W2, float* __restrict__ h2s, int N)
{
    __shared__ unsigned short Wl[F * F];   // bf16 W1, 32 KB
    for (int idx = threadIdx.x; idx < F * F; idx += 512)
        Wl[idx] = f2bf(W1[idx]);
    __syncthreads();

    int wave = threadIdx.x >> 6, lane = threadIdx.x & 63;
    int half = lane >> 5, c = lane & 31;
    int node0 = (blockIdx.x * 8 + wave) * 4;
    if (node0 >= N) return;

    int bg[4], dg[4];
    float dv[4];
    int maxdeg = 0;
#pragma unroll
    for (int n = 0; n < 4; ++n) {
        int i = node0 + n;
        int b = (i < N) ? rp[i] : 0;
        int e = (i < N) ? rp[i + 1] : 0;
        bg[n] = rfl(b);
        dg[n] = rfl(e - b);
        dv[n] = (i < N) ? dinv[i] : 0.f;
        maxdeg = maxdeg > dg[n] ? maxdeg : dg[n];
    }
    int tmax = (maxdeg + 1) >> 1;

    // acc[n][j]: partial sum of feature 4c+j over this half's edges
    float acc[4][4] = {};
    for (int t = 0; t < tmax; ++t) {
#pragma unroll
        for (int n = 0; n < 4; ++n) {
            int k = 2 * t + half;
            if (k < dg[n]) {
                int s = col[bg[n] + k];
                ushort4 v = *reinterpret_cast<const ushort4*>(xs + (size_t)s * F + 4 * c);
                acc[n][0] += bf2f(v.x);
                acc[n][1] += bf2f(v.y);
                acc[n][2] += bf2f(v.z);
                acc[n][3] += bf2f(v.w);
            }
        }
    }

    // combine halves; scale by dinv_i. xa feature 4c+j lives at lanes c and c+32.
#pragma unroll
    for (int n = 0; n < 4; ++n)
#pragma unroll
        for (int j = 0; j < 4; ++j) {
            acc[n][j] += __shfl_xor(acc[n][j], 32);
            acc[n][j] *= dv[n];
        }

    // matvec: lane owns output columns 2*lane, 2*lane+1 (packed bf16 weight reads)
    const unsigned int* Wl32 = reinterpret_cast<const unsigned int*>(Wl);
    float o0[4] = {}, o1[4] = {};
#pragma unroll 2
    for (int c2 = 0; c2 < 32; ++c2) {
#pragma unroll
        for (int j = 0; j < 4; ++j) {
            unsigned int w = Wl32[(4 * c2 + j) * (F / 2) + lane];
            float wlo = bf2f((unsigned short)(w & 0xffff));
            float whi = bf2f((unsigned short)(w >> 16));
#pragma unroll
            for (int n = 0; n < 4; ++n) {
                float xk = rl(acc[n][j], c2);
                o0[n] += xk * wlo;
                o1[n] += xk * whi;
            }
        }
    }

    float2 b1v = ((const float2*)b1)[lane];
    float2 w2v = ((const float2*)W2)[lane];
#pragma unroll
    for (int n = 0; n < 4; ++n) {
        int i = node0 + n;
        float v0 = fmaxf(o0[n] + b1v.x, 0.f);
        float v1 = fmaxf(o1[n] + b1v.y, 0.f);
        float dot = v0 * w2v.x + v1 * w2v.y;
#pragma unroll
        for (int off = 32; off; off >>= 1) dot += __shfl_down(dot, off);
        if (lane == 0 && i < N) h2s[i] = dv[n] * dot;
    }
}

// ------- layer 2 aggregation: h2[i] = dinv_i * sum(h2s[neigh]) + b2 -------
// One wave per node; coalesced col reads, L2-resident h2s gathers.

__global__ __launch_bounds__(256) void agg2(
    const float* __restrict__ h2s, const int* __restrict__ rp,
    const int* __restrict__ col, const float* __restrict__ dinv,
    const float* __restrict__ b2, float* __restrict__ h2, int N)
{
    int wid = (blockIdx.x * 256 + threadIdx.x) >> 6;
    int lane = threadIdx.x & 63;
    if (wid >= N) return;
    int beg = rfl(rp[wid]);
    int end = rfl(rp[wid + 1]);
    float s = 0.f;
    for (int e = beg + lane; e < end; e += 64)
        s += h2s[col[e]];
#pragma unroll
    for (int off = 32; off; off >>= 1) s += __shfl_xor(s, off);
    if (lane == 0) h2[wid] = dinv[wid] * s + b2[0];
}

// ------- edge probabilities -------

__global__ void edge_probs(const int* __restrict__ src, const int* __restrict__ dst,
                           const float* __restrict__ h2, float* __restrict__ out, int E) {
    int e = blockIdx.x * blockDim.x + threadIdx.x;
    if (e >= E) return;
    float v = h2[src[e]] * h2[dst[e]];
    out[e] = 1.0f / (1.0f + expf(-v));
}

// ---------------- launch ----------------

extern "C" void kernel_launch(void* const* d_in, const int* in_sizes, int n_in,
                              void* d_out, int out_size, void* d_ws, size_t ws_size,
                              hipStream_t stream) {
    const float* x  = (const float*)d_in[0];
    const int*   ei = (const int*)d_in[1];       // int32 (JAX x64 disabled)
    const float* W1 = (const float*)d_in[2];
    const float* b1 = (const float*)d_in[3];
    const float* W2 = (const float*)d_in[4];
    const float* b2 = (const float*)d_in[5];
    float* out = (float*)d_out;

    int N = in_sizes[0] / F;
    int E = in_sizes[1] / 2;
    const int* src = ei;
    const int* dst = ei + E;
    int total = E + N;

    // workspace layout (~42 MB)
    char* ws = (char*)d_ws;
    size_t off = 0;
    auto alloc = [&](size_t bytes) -> void* {
        off = (off + 255) & ~(size_t)255;
        void* p = ws + off;
        off += bytes;
        return p;
    };
    int*   deg   = (int*)alloc((size_t)N * 4);
    float* dinv  = (float*)alloc((size_t)N * 4);
    int*   rp    = (int*)alloc((size_t)(N + 1) * 4);
    int*   fill  = (int*)alloc((size_t)N * 4);
    int*   bsums = (int*)alloc(128 * 4);
    int*   col   = (int*)alloc((size_t)total * 4);
    unsigned short* xsb = (unsigned short*)alloc((size_t)N * F * 2);
    float* h2s   = (float*)alloc((size_t)N * 4);
    float* h2    = (float*)alloc((size_t)N * 4);
    (void)ws_size;

    int nb = (N + 1023) / 1024;

    zero_i32<<<(N + 255) / 256, 256, 0, stream>>>(deg, N);
    zero_i32<<<(N + 255) / 256, 256, 0, stream>>>(fill, N);
    count_deg<<<(total + 255) / 256, 256, 0, stream>>>(dst, E, N, deg);
    compute_dinv<<<(N + 255) / 256, 256, 0, stream>>>(deg, dinv, N);
    scan_block<<<nb, 1024, 0, stream>>>(deg, rp, bsums, N);
    scan_sums<<<1, 128, 0, stream>>>(bsums, nb);
    scan_add<<<nb, 1024, 0, stream>>>(rp, bsums, N, total);
    fill_csr<<<(total + 255) / 256, 256, 0, stream>>>(src, dst, E, N, rp, fill, col);
    prescale<<<(N * (F / 4) + 255) / 256, 256, 0, stream>>>(x, dinv, xsb, N);
    fused1<<<(N + 31) / 32, 512, 0, stream>>>(xsb, rp, col, dinv, b1, W1, W2, h2s, N);
    agg2<<<((N * 64) + 255) / 256, 256, 0, stream>>>(h2s, rp, col, dinv, b2, h2, N);
    edge_probs<<<(E + 255) / 256, 256, 0, stream>>>(src, dst, h2, out, E);
}

// Round 4
// 520.824 us; speedup vs baseline: 1.9625x; 1.2872x over previous
//
#include <hip/hip_runtime.h>
#include <hip/hip_bf16.h>
#include <math.h>

#define F 128

typedef short bf16x8 __attribute__((ext_vector_type(8)));
typedef float f32x4 __attribute__((ext_vector_type(4)));

__device__ __forceinline__ int rfl(int v) { return __builtin_amdgcn_readfirstlane(v); }
__device__ __forceinline__ unsigned short f2bf(float f) {
    __hip_bfloat16 h = __float2bfloat16(f);
    return *reinterpret_cast<unsigned short*>(&h);
}
__device__ __forceinline__ float bf2f(unsigned short u) {
    return __uint_as_float((unsigned)u << 16);
}
__device__ __forceinline__ unsigned pack2(float lo, float hi) {
    return (unsigned)f2bf(lo) | ((unsigned)f2bf(hi) << 16);
}

// ---------------- utility ----------------

__global__ void zero_i32(int* __restrict__ p, int n) {
    int i = blockIdx.x * blockDim.x + threadIdx.x;
    if (i < n) p[i] = 0;
}

// ---------------- CSR build ----------------
// pass 1: per-edge local rank within its dst row (single atomic pass)
__global__ void count_off(const int* __restrict__ dst, int E,
                          int* __restrict__ deg, int* __restrict__ lo) {
    int e = blockIdx.x * blockDim.x + threadIdx.x;
    if (e >= E) return;
    lo[e] = atomicAdd(&deg[dst[e]], 1);
}

// scan over (deg+1) -> rp partial; also writes dinv = rsqrt(deg+1)
__global__ __launch_bounds__(1024) void scan_block(const int* __restrict__ deg,
                                                   int* __restrict__ out,
                                                   int* __restrict__ bsums,
                                                   float* __restrict__ dinv, int N) {
    __shared__ int tmp[1024];
    int t = threadIdx.x;
    int gid = blockIdx.x * 1024 + t;
    int v = 0;
    if (gid < N) {
        v = deg[gid] + 1;                       // +1 self-loop
        dinv[gid] = rsqrtf((float)v);
    }
    tmp[t] = v;
    __syncthreads();
    for (int off = 1; off < 1024; off <<= 1) {
        int add = (t >= off) ? tmp[t - off] : 0;
        __syncthreads();
        tmp[t] += add;
        __syncthreads();
    }
    if (gid < N) out[gid] = tmp[t] - v;         // exclusive within block
    if (t == 1023) bsums[blockIdx.x] = tmp[t];
}

__global__ __launch_bounds__(128) void scan_sums(int* __restrict__ bsums, int nb) {
    __shared__ int tmp[128];
    int t = threadIdx.x;
    int v = (t < nb) ? bsums[t] : 0;
    tmp[t] = v;
    __syncthreads();
    for (int off = 1; off < 128; off <<= 1) {
        int add = (t >= off) ? tmp[t - off] : 0;
        __syncthreads();
        tmp[t] += add;
        __syncthreads();
    }
    if (t < nb) bsums[t] = tmp[t] - v;          // exclusive over blocks
}

__global__ __launch_bounds__(1024) void scan_add(int* __restrict__ rp,
                                                 const int* __restrict__ bsums,
                                                 int N, int total) {
    int t = threadIdx.x;
    int gid = blockIdx.x * 1024 + t;
    if (gid < N) rp[gid] += bsums[blockIdx.x];
    if (gid == 0) rp[N] = total;
}

// pass 2: pure scatter (no atomics); self-loop gets slot rp[n]+deg[n] (= rp[n+1]-1)
__global__ void fill_csr(const int* __restrict__ src, const int* __restrict__ dst,
                         const int* __restrict__ lo, const int* __restrict__ rp,
                         const int* __restrict__ deg, int* __restrict__ col,
                         int E, int N) {
    int i = blockIdx.x * blockDim.x + threadIdx.x;
    if (i < E) {
        col[rp[dst[i]] + lo[i]] = src[i];
    } else if (i < E + N) {
        int n = i - E;
        col[rp[n] + deg[n]] = n;
    }
}

// ------- W1 -> bf16, transposed [j][k], XOR-swizzled bytes (once) -------
__global__ void w1prep(const float* __restrict__ W1, unsigned char* __restrict__ W1t) {
    int tid = blockIdx.x * blockDim.x + threadIdx.x;   // tid = j*128 + k
    if (tid >= F * F) return;
    int j = tid >> 7, k = tid & 127;
    unsigned short w = f2bf(W1[k * F + j]);
    int ofs = (j << 8) + (((k << 1)) ^ ((j & 7) << 4));
    *reinterpret_cast<unsigned short*>(W1t + ofs) = w;
}

// ------- prescale: xs[n][f] = bf16(dinv[n] * x[n][f]) -------
__global__ void prescale(const float* __restrict__ x, const float* __restrict__ dinv,
                         unsigned short* __restrict__ xs, int N) {
    int i = blockIdx.x * blockDim.x + threadIdx.x;   // float4 group index
    int ngroups = N * (F / 4);
    if (i >= ngroups) return;
    int row = i >> 5;
    float d = dinv[row];
    float4 v = ((const float4*)x)[i];
    ushort4 o;
    o.x = f2bf(v.x * d); o.y = f2bf(v.y * d);
    o.z = f2bf(v.z * d); o.w = f2bf(v.w * d);
    ((ushort4*)xs)[i] = o;
}

// ------- fused layer 1: gather-aggregate 32 nodes -> LDS -> MFMA MLP -> h2s -------
// 8 waves/block, 4 nodes/wave. MFMA: A = 16 nodes x 32k (XA), B = 32k x 16j (W1t).
__global__ __launch_bounds__(512) void fused1(
    const unsigned short* __restrict__ xs, const int* __restrict__ rp,
    const int* __restrict__ col, const float* __restrict__ dinv,
    const float* __restrict__ b1, const float* __restrict__ W2,
    const unsigned char* __restrict__ W1t_g, float* __restrict__ h2s, int N)
{
    __shared__ unsigned char W1t[F * F * 2];   // 32 KB, [j][k] bf16 swizzled
    __shared__ unsigned char XA[32 * F * 2];   // 8 KB, [node][k] bf16 swizzled
    __shared__ float part[2][16][4];

    // stage pre-swizzled W1t (linear copy)
    for (int idx = threadIdx.x; idx < (F * F * 2) / 16; idx += 512)
        ((int4*)W1t)[idx] = ((const int4*)W1t_g)[idx];

    int wave = threadIdx.x >> 6, lane = threadIdx.x & 63;
    int half = lane >> 5, c = lane & 31;
    int node0 = blockIdx.x * 32 + wave * 4;

    int bg[4], dg[4];
    float dv[4];
    int maxdeg = 0;
#pragma unroll
    for (int n = 0; n < 4; ++n) {
        int i = node0 + n;
        int b = (i < N) ? rp[i] : 0;
        int e2 = (i < N) ? rp[i + 1] : 0;
        bg[n] = rfl(b);
        dg[n] = rfl(e2 - b);
        dv[n] = (i < N) ? dinv[i] : 0.f;
        maxdeg = maxdeg > dg[n] ? maxdeg : dg[n];
    }
    int tmax = (maxdeg + 1) >> 1;

    float acc[4][4] = {};
#pragma unroll 2
    for (int t = 0; t < tmax; ++t) {
#pragma unroll
        for (int n = 0; n < 4; ++n) {
            int k = 2 * t + half;
            if (k < dg[n]) {
                int s = col[bg[n] + k];
                ushort4 v = *reinterpret_cast<const ushort4*>(xs + (size_t)s * F + 4 * c);
                acc[n][0] += bf2f(v.x);
                acc[n][1] += bf2f(v.y);
                acc[n][2] += bf2f(v.z);
                acc[n][3] += bf2f(v.w);
            }
        }
    }
#pragma unroll
    for (int n = 0; n < 4; ++n)
#pragma unroll
        for (int j2 = 0; j2 < 4; ++j2) {
            acc[n][j2] += __shfl_xor(acc[n][j2], 32);
            acc[n][j2] *= dv[n];
        }

    // write xa (bf16) to XA: half h writes nodes 2h, 2h+1; feature 4c+j at byte 8c
#pragma unroll
    for (int nn = 0; nn < 2; ++nn) {
        int n = half * 2 + nn;
        int nl = wave * 4 + n;
        unsigned u0 = pack2(acc[n][0], acc[n][1]);
        unsigned u1 = pack2(acc[n][2], acc[n][3]);
        int ofs = nl * 256 + ((8 * c) ^ ((nl & 7) << 4));
        *reinterpret_cast<uint2*>(XA + ofs) = make_uint2(u0, u1);
    }
    __syncthreads();

    // MFMA: wave w -> node-group g = w>>2, j-tiles {2(w&3), 2(w&3)+1}
    int g = wave >> 2, jt0 = (wave & 3) * 2;
    int l15 = lane & 15;
    int kb = (lane >> 4) * 16;

    bf16x8 afr[4];
    int arow = g * 16 + l15;
#pragma unroll
    for (int kk = 0; kk < 4; ++kk) {
        int ofs = arow * 256 + ((kk * 64 + kb) ^ ((arow & 7) << 4));
        afr[kk] = *reinterpret_cast<const bf16x8*>(XA + ofs);
    }

    float p[4] = {0.f, 0.f, 0.f, 0.f};
#pragma unroll
    for (int jj = 0; jj < 2; ++jj) {
        int j = (jt0 + jj) * 16 + l15;
        f32x4 d = {0.f, 0.f, 0.f, 0.f};
#pragma unroll
        for (int kk = 0; kk < 4; ++kk) {
            int ofs = j * 256 + ((kk * 64 + kb) ^ ((j & 7) << 4));
            bf16x8 bfr = *reinterpret_cast<const bf16x8*>(W1t + ofs);
            d = __builtin_amdgcn_mfma_f32_16x16x32_bf16(afr[kk], bfr, d, 0, 0, 0);
        }
        float bj = b1[j], wj = W2[j];
#pragma unroll
        for (int r = 0; r < 4; ++r) {
            float v = fmaxf(d[r] + bj, 0.f);
            p[r] += v * wj;
        }
    }
#pragma unroll
    for (int r = 0; r < 4; ++r) {
        p[r] += __shfl_xor(p[r], 1);
        p[r] += __shfl_xor(p[r], 2);
        p[r] += __shfl_xor(p[r], 4);
        p[r] += __shfl_xor(p[r], 8);
    }
    if (l15 == 0) {
#pragma unroll
        for (int r = 0; r < 4; ++r)
            part[g][(lane >> 4) * 4 + r][wave & 3] = p[r];
    }
    __syncthreads();

    if (threadIdx.x < 32) {
        int i = blockIdx.x * 32 + threadIdx.x;
        if (i < N) {
            const float* q = part[threadIdx.x >> 4][threadIdx.x & 15];
            h2s[i] = dinv[i] * (q[0] + q[1] + q[2] + q[3]);
        }
    }
}

// ------- layer 2 aggregation: h2[i] = dinv_i * sum(h2s[neigh]) + b2 -------
// half-wave (32 lanes) per node
__global__ __launch_bounds__(256) void agg2(
    const float* __restrict__ h2s, const int* __restrict__ rp,
    const int* __restrict__ col, const float* __restrict__ dinv,
    const float* __restrict__ b2, float* __restrict__ h2, int N)
{
    int nid = (blockIdx.x * 256 + threadIdx.x) >> 5;
    int c = threadIdx.x & 31;
    if (nid >= N) return;
    int beg = rfl(rp[nid]);
    int end = rfl(rp[nid + 1]);
    float s = 0.f;
    for (int e = beg + c; e < end; e += 32)
        s += h2s[col[e]];
#pragma unroll
    for (int off = 16; off; off >>= 1) s += __shfl_xor(s, off);
    if (c == 0) h2[nid] = dinv[nid] * s + b2[0];
}

// ------- edge probabilities -------
__global__ void edge_probs(const int* __restrict__ src, const int* __restrict__ dst,
                           const float* __restrict__ h2, float* __restrict__ out, int E) {
    int e = blockIdx.x * blockDim.x + threadIdx.x;
    if (e >= E) return;
    float v = h2[src[e]] * h2[dst[e]];
    out[e] = 1.0f / (1.0f + expf(-v));
}

// ---------------- launch ----------------

extern "C" void kernel_launch(void* const* d_in, const int* in_sizes, int n_in,
                              void* d_out, int out_size, void* d_ws, size_t ws_size,
                              hipStream_t stream) {
    const float* x  = (const float*)d_in[0];
    const int*   ei = (const int*)d_in[1];       // int32 (JAX x64 disabled)
    const float* W1 = (const float*)d_in[2];
    const float* b1 = (const float*)d_in[3];
    const float* W2 = (const float*)d_in[4];
    const float* b2 = (const float*)d_in[5];
    float* out = (float*)d_out;

    int N = in_sizes[0] / F;
    int E = in_sizes[1] / 2;
    const int* src = ei;
    const int* dst = ei + E;
    int total = E + N;

    // workspace (~41 MB); lo (edge ranks) aliases xs (prescale runs after fill)
    char* ws = (char*)d_ws;
    size_t off = 0;
    auto alloc = [&](size_t bytes) -> void* {
        off = (off + 255) & ~(size_t)255;
        void* p = ws + off;
        off += bytes;
        return p;
    };
    int*   deg   = (int*)alloc((size_t)N * 4);
    float* dinv  = (float*)alloc((size_t)N * 4);
    int*   rp    = (int*)alloc((size_t)(N + 1) * 4);
    int*   bsums = (int*)alloc(128 * 4);
    int*   col   = (int*)alloc((size_t)total * 4);
    unsigned char* W1tg = (unsigned char*)alloc(F * F * 2);
    float* h2s   = (float*)alloc((size_t)N * 4);
    float* h2    = (float*)alloc((size_t)N * 4);
    size_t uniBytes = (size_t)E * 4;
    size_t xsBytes = (size_t)N * F * 2;
    if (xsBytes > uniBytes) uniBytes = xsBytes;
    void* uni = alloc(uniBytes);
    int* lo = (int*)uni;
    unsigned short* xs = (unsigned short*)uni;
    (void)ws_size;

    int nb = (N + 1023) / 1024;

    zero_i32<<<(N + 255) / 256, 256, 0, stream>>>(deg, N);
    count_off<<<(E + 255) / 256, 256, 0, stream>>>(dst, E, deg, lo);
    scan_block<<<nb, 1024, 0, stream>>>(deg, rp, bsums, dinv, N);
    scan_sums<<<1, 128, 0, stream>>>(bsums, nb);
    scan_add<<<nb, 1024, 0, stream>>>(rp, bsums, N, total);
    fill_csr<<<(total + 255) / 256, 256, 0, stream>>>(src, dst, lo, rp, deg, col, E, N);
    w1prep<<<(F * F + 255) / 256, 256, 0, stream>>>(W1, W1tg);
    prescale<<<(N * (F / 4) + 255) / 256, 256, 0, stream>>>(x, dinv, xs, N);
    fused1<<<(N + 31) / 32, 512, 0, stream>>>(xs, rp, col, dinv, b1, W2, W1tg, h2s, N);
    agg2<<<((size_t)N * 32 + 255) / 256, 256, 0, stream>>>(h2s, rp, col, dinv, b2, h2, N);
    edge_probs<<<(E + 255) / 256, 256, 0, stream>>>(src, dst, h2, out, E);
}

// Round 5
// 389.466 us; speedup vs baseline: 2.6245x; 1.3373x over previous
//
#include <hip/hip_runtime.h>
#include <hip/hip_bf16.h>
#include <math.h>

#define F 128

typedef short bf16x8 __attribute__((ext_vector_type(8)));
typedef float f32x4 __attribute__((ext_vector_type(4)));
typedef float f32x2 __attribute__((ext_vector_type(2)));

__device__ __forceinline__ int rfl(int v) { return __builtin_amdgcn_readfirstlane(v); }
__device__ __forceinline__ unsigned short f2bf(float f) {
    __hip_bfloat16 h = __float2bfloat16(f);
    return *reinterpret_cast<unsigned short*>(&h);
}
__device__ __forceinline__ unsigned pack2(float lo, float hi) {
    return (unsigned)f2bf(lo) | ((unsigned)f2bf(hi) << 16);
}

// ---------------- utility ----------------

__global__ void zero_i32(int* __restrict__ p, int n) {
    int i = blockIdx.x * blockDim.x + threadIdx.x;
    if (i < n) p[i] = 0;
}

// ---------------- CSR build ----------------
__global__ void count_off(const int* __restrict__ dst, int E,
                          int* __restrict__ deg, int* __restrict__ lo) {
    int e = blockIdx.x * blockDim.x + threadIdx.x;
    if (e >= E) return;
    lo[e] = atomicAdd(&deg[dst[e]], 1);
}

__global__ __launch_bounds__(1024) void scan_block(const int* __restrict__ deg,
                                                   int* __restrict__ out,
                                                   int* __restrict__ bsums,
                                                   float* __restrict__ dinv, int N) {
    __shared__ int tmp[1024];
    int t = threadIdx.x;
    int gid = blockIdx.x * 1024 + t;
    int v = 0;
    if (gid < N) {
        v = deg[gid] + 1;                       // +1 self-loop
        dinv[gid] = rsqrtf((float)v);
    }
    tmp[t] = v;
    __syncthreads();
    for (int off = 1; off < 1024; off <<= 1) {
        int add = (t >= off) ? tmp[t - off] : 0;
        __syncthreads();
        tmp[t] += add;
        __syncthreads();
    }
    if (gid < N) out[gid] = tmp[t] - v;
    if (t == 1023) bsums[blockIdx.x] = tmp[t];
}

__global__ __launch_bounds__(128) void scan_sums(int* __restrict__ bsums, int nb) {
    __shared__ int tmp[128];
    int t = threadIdx.x;
    int v = (t < nb) ? bsums[t] : 0;
    tmp[t] = v;
    __syncthreads();
    for (int off = 1; off < 128; off <<= 1) {
        int add = (t >= off) ? tmp[t - off] : 0;
        __syncthreads();
        tmp[t] += add;
        __syncthreads();
    }
    if (t < nb) bsums[t] = tmp[t] - v;
}

__global__ __launch_bounds__(1024) void scan_add(int* __restrict__ rp,
                                                 const int* __restrict__ bsums,
                                                 int N, int total) {
    int t = threadIdx.x;
    int gid = blockIdx.x * 1024 + t;
    if (gid < N) rp[gid] += bsums[blockIdx.x];
    if (gid == 0) rp[N] = total;
}

__global__ void fill_csr(const int* __restrict__ src, const int* __restrict__ dst,
                         const int* __restrict__ lo, const int* __restrict__ rp,
                         const int* __restrict__ deg, int* __restrict__ col,
                         int E, int N) {
    int i = blockIdx.x * blockDim.x + threadIdx.x;
    if (i < E) {
        col[rp[dst[i]] + lo[i]] = src[i];
    } else if (i < E + N) {
        int n = i - E;
        col[rp[n] + deg[n]] = n;
    }
}

// ------- W1 -> bf16, transposed [j][k], XOR-swizzled bytes (once) -------
__global__ void w1prep(const float* __restrict__ W1, unsigned char* __restrict__ W1t) {
    int tid = blockIdx.x * blockDim.x + threadIdx.x;   // tid = j*128 + k
    if (tid >= F * F) return;
    int j = tid >> 7, k = tid & 127;
    unsigned short w = f2bf(W1[k * F + j]);
    int ofs = (j << 8) + (((k << 1)) ^ ((j & 7) << 4));
    *reinterpret_cast<unsigned short*>(W1t + ofs) = w;
}

// ------- prescale: xsq[p][n][32] = fp8(dinv[n]*x[n][32p..32p+31]) -------
__global__ void prescale(const float* __restrict__ x, const float* __restrict__ dinv,
                         unsigned char* __restrict__ xsq, int N) {
    int i = blockIdx.x * blockDim.x + threadIdx.x;   // float4 group: n*32+g
    if (i >= N * 32) return;
    int n = i >> 5, g = i & 31;
    int p = g >> 3, q = g & 7;
    float d = dinv[n];
    float4 v = ((const float4*)x)[i];
    int r = __builtin_amdgcn_cvt_pk_fp8_f32(v.x * d, v.y * d, 0, false);
    r = __builtin_amdgcn_cvt_pk_fp8_f32(v.z * d, v.w * d, r, true);
    *reinterpret_cast<unsigned*>(xsq + (size_t)p * N * 32 + (size_t)n * 32 + 4 * q) = r;
}

// ------- aggregation pass: xa[n][32p..] = dinv_n * sum_s fp8row(s) -------
// Pass p = blockIdx.x / nbp; quarter working set 3.2 MB -> L2-resident.
// 4 waves/block, 4 nodes/wave; octet (8 lanes) per edge, 4 features/lane.
__global__ __launch_bounds__(256) void agg1(
    const unsigned char* __restrict__ xsq, const int* __restrict__ rp,
    const int* __restrict__ col, const float* __restrict__ dinv,
    unsigned short* __restrict__ xa, int N, int nbp)
{
    int p = blockIdx.x / nbp;
    int blk = blockIdx.x - p * nbp;
    int wave = threadIdx.x >> 6, lane = threadIdx.x & 63;
    int o = lane >> 3, c8 = lane & 7;
    int node0 = blk * 16 + wave * 4;
    if (node0 >= N) return;
    const unsigned char* xsp = xsq + (size_t)p * N * 32;

    int bg[4], dg[4];
    float dv[4];
    int maxdeg = 0;
#pragma unroll
    for (int n = 0; n < 4; ++n) {
        int i = node0 + n;
        int b = (i < N) ? rp[i] : 0;
        int e2 = (i < N) ? rp[i + 1] : 0;
        bg[n] = rfl(b);
        dg[n] = rfl(e2 - b);
        dv[n] = (i < N) ? dinv[i] : 0.f;
        maxdeg = maxdeg > dg[n] ? maxdeg : dg[n];
    }

    f32x2 acc[4][2] = {};
    for (int base = 0; base < maxdeg; base += 64) {
        int colv[4];
#pragma unroll
        for (int n = 0; n < 4; ++n)
            colv[n] = (base + lane < dg[n]) ? col[bg[n] + base + lane] : 0;
        int cm = maxdeg - base; if (cm > 64) cm = 64;
        int tm = (cm + 7) >> 3;
        for (int t = 0; t < tm; ++t) {
            int k = (t << 3) + o;
#pragma unroll
            for (int n = 0; n < 4; ++n) {
                if (base + k < dg[n]) {
                    int s = __shfl(colv[n], k);
                    unsigned u = *reinterpret_cast<const unsigned*>(xsp + (size_t)s * 32 + 4 * c8);
                    acc[n][0] += __builtin_amdgcn_cvt_pk_f32_fp8(u, false);
                    acc[n][1] += __builtin_amdgcn_cvt_pk_f32_fp8(u, true);
                }
            }
        }
    }

    // reduce partials across the 8 octets (same features, different edges)
    float red[4][4];
#pragma unroll
    for (int n = 0; n < 4; ++n) {
        red[n][0] = acc[n][0].x; red[n][1] = acc[n][0].y;
        red[n][2] = acc[n][1].x; red[n][3] = acc[n][1].y;
#pragma unroll
        for (int j = 0; j < 4; ++j) {
            red[n][j] += __shfl_xor(red[n][j], 8);
            red[n][j] += __shfl_xor(red[n][j], 16);
            red[n][j] += __shfl_xor(red[n][j], 32);
        }
    }

    // octet o<4 writes node node0+o, features 32p+4*c8 .. +3 (bf16)
    if (o < 4) {
        int i = node0 + o;
        if (i < N) {
            float d = dv[o];
            unsigned lo = pack2(red[o][0] * d, red[o][1] * d);
            unsigned hi = pack2(red[o][2] * d, red[o][3] * d);
            *reinterpret_cast<uint2*>(xa + (size_t)i * F + p * 32 + 4 * c8) =
                make_uint2(lo, hi);
        }
    }
}

// ------- MLP: h2s[i] = dinv_i * (relu(xa@W1 + b1) @ W2) via MFMA -------
__global__ __launch_bounds__(512) void mlp(
    const unsigned short* __restrict__ xa, const float* __restrict__ dinv,
    const float* __restrict__ b1, const float* __restrict__ W2,
    const unsigned char* __restrict__ W1t_g, float* __restrict__ h2s, int N)
{
    __shared__ unsigned char W1t[F * F * 2];   // 32 KB swizzled [j][k]
    __shared__ unsigned char XA[32 * 256];     // 8 KB swizzled [node][k]
    __shared__ float part[2][16][4];

    for (int idx = threadIdx.x; idx < (F * F * 2) / 16; idx += 512)
        ((int4*)W1t)[idx] = ((const int4*)W1t_g)[idx];

    {   // stage 32 node rows, swizzled
        int r = threadIdx.x >> 4, t16 = threadIdx.x & 15;
        int gi = blockIdx.x * 32 + r;
        uint4 v = make_uint4(0, 0, 0, 0);
        if (gi < N) v = *reinterpret_cast<const uint4*>(xa + (size_t)gi * F + 8 * t16);
        *reinterpret_cast<uint4*>(XA + r * 256 + ((16 * t16) ^ ((r & 7) << 4))) = v;
    }
    __syncthreads();

    int wave = threadIdx.x >> 6, lane = threadIdx.x & 63;
    int g = wave >> 2, jt0 = (wave & 3) * 2;
    int l15 = lane & 15;
    int kb = (lane >> 4) * 16;

    bf16x8 afr[4];
    int arow = g * 16 + l15;
#pragma unroll
    for (int kk = 0; kk < 4; ++kk) {
        int ofs = arow * 256 + ((kk * 64 + kb) ^ ((arow & 7) << 4));
        afr[kk] = *reinterpret_cast<const bf16x8*>(XA + ofs);
    }

    float p[4] = {0.f, 0.f, 0.f, 0.f};
#pragma unroll
    for (int jj = 0; jj < 2; ++jj) {
        int j = (jt0 + jj) * 16 + l15;
        f32x4 d = {0.f, 0.f, 0.f, 0.f};
#pragma unroll
        for (int kk = 0; kk < 4; ++kk) {
            int ofs = j * 256 + ((kk * 64 + kb) ^ ((j & 7) << 4));
            bf16x8 bfr = *reinterpret_cast<const bf16x8*>(W1t + ofs);
            d = __builtin_amdgcn_mfma_f32_16x16x32_bf16(afr[kk], bfr, d, 0, 0, 0);
        }
        float bj = b1[j], wj = W2[j];
#pragma unroll
        for (int r = 0; r < 4; ++r) {
            float v = fmaxf(d[r] + bj, 0.f);
            p[r] += v * wj;
        }
    }
#pragma unroll
    for (int r = 0; r < 4; ++r) {
        p[r] += __shfl_xor(p[r], 1);
        p[r] += __shfl_xor(p[r], 2);
        p[r] += __shfl_xor(p[r], 4);
        p[r] += __shfl_xor(p[r], 8);
    }
    if (l15 == 0) {
#pragma unroll
        for (int r = 0; r < 4; ++r)
            part[g][(lane >> 4) * 4 + r][wave & 3] = p[r];
    }
    __syncthreads();

    if (threadIdx.x < 32) {
        int i = blockIdx.x * 32 + threadIdx.x;
        if (i < N) {
            const float* q = part[threadIdx.x >> 4][threadIdx.x & 15];
            h2s[i] = dinv[i] * (q[0] + q[1] + q[2] + q[3]);
        }
    }
}

// ------- layer 2 aggregation: quarter-wave (16 lanes) per node -------
__global__ __launch_bounds__(256) void agg2(
    const float* __restrict__ h2s, const int* __restrict__ rp,
    const int* __restrict__ col, const float* __restrict__ dinv,
    const float* __restrict__ b2, float* __restrict__ h2, int N)
{
    int nid = (blockIdx.x * 256 + threadIdx.x) >> 4;
    int c = threadIdx.x & 15;
    if (nid >= N) return;
    int beg = rfl(rp[nid]);
    int end = rfl(rp[nid + 1]);
    float s = 0.f;
    for (int e = beg + c; e < end; e += 16)
        s += h2s[col[e]];
#pragma unroll
    for (int off = 8; off; off >>= 1) s += __shfl_xor(s, off);
    if (c == 0) h2[nid] = dinv[nid] * s + b2[0];
}

// ------- edge probabilities -------
__global__ void edge_probs(const int* __restrict__ src, const int* __restrict__ dst,
                           const float* __restrict__ h2, float* __restrict__ out, int E) {
    int e = blockIdx.x * blockDim.x + threadIdx.x;
    if (e >= E) return;
    float v = h2[src[e]] * h2[dst[e]];
    out[e] = 1.0f / (1.0f + __expf(-v));
}

// ---------------- launch ----------------

extern "C" void kernel_launch(void* const* d_in, const int* in_sizes, int n_in,
                              void* d_out, int out_size, void* d_ws, size_t ws_size,
                              hipStream_t stream) {
    const float* x  = (const float*)d_in[0];
    const int*   ei = (const int*)d_in[1];       // int32 (JAX x64 disabled)
    const float* W1 = (const float*)d_in[2];
    const float* b1 = (const float*)d_in[3];
    const float* W2 = (const float*)d_in[4];
    const float* b2 = (const float*)d_in[5];
    float* out = (float*)d_out;

    int N = in_sizes[0] / F;
    int E = in_sizes[1] / 2;
    const int* src = ei;
    const int* dst = ei + E;
    int total = E + N;

    // workspace (~54 MB); lo (edge ranks) aliases xsq (prescale runs after fill_csr)
    char* ws = (char*)d_ws;
    size_t off = 0;
    auto alloc = [&](size_t bytes) -> void* {
        off = (off + 255) & ~(size_t)255;
        void* p = ws + off;
        off += bytes;
        return p;
    };
    int*   deg   = (int*)alloc((size_t)N * 4);
    float* dinv  = (float*)alloc((size_t)N * 4);
    int*   rp    = (int*)alloc((size_t)(N + 1) * 4);
    int*   bsums = (int*)alloc(128 * 4);
    int*   col   = (int*)alloc((size_t)total * 4);
    unsigned char* W1tg = (unsigned char*)alloc(F * F * 2);
    unsigned short* xa  = (unsigned short*)alloc((size_t)N * F * 2);
    float* h2s   = (float*)alloc((size_t)N * 4);
    float* h2    = (float*)alloc((size_t)N * 4);
    size_t uniBytes = (size_t)E * 4;
    size_t xsqBytes = (size_t)N * 32 * 4;
    if (xsqBytes > uniBytes) uniBytes = xsqBytes;
    void* uni = alloc(uniBytes);
    int* lo = (int*)uni;
    unsigned char* xsq = (unsigned char*)uni;
    (void)ws_size;

    int nb = (N + 1023) / 1024;
    int nbp = (N + 15) / 16;    // agg1 blocks per pass

    zero_i32<<<(N + 255) / 256, 256, 0, stream>>>(deg, N);
    count_off<<<(E + 255) / 256, 256, 0, stream>>>(dst, E, deg, lo);
    scan_block<<<nb, 1024, 0, stream>>>(deg, rp, bsums, dinv, N);
    scan_sums<<<1, 128, 0, stream>>>(bsums, nb);
    scan_add<<<nb, 1024, 0, stream>>>(rp, bsums, N, total);
    fill_csr<<<(total + 255) / 256, 256, 0, stream>>>(src, dst, lo, rp, deg, col, E, N);
    w1prep<<<(F * F + 255) / 256, 256, 0, stream>>>(W1, W1tg);
    prescale<<<(N * 32 + 255) / 256, 256, 0, stream>>>(x, dinv, xsq, N);
    agg1<<<4 * nbp, 256, 0, stream>>>(xsq, rp, col, dinv, xa, N, nbp);
    mlp<<<(N + 31) / 32, 512, 0, stream>>>(xa, dinv, b1, W2, W1tg, h2s, N);
    agg2<<<((size_t)N * 16 + 255) / 256, 256, 0, stream>>>(h2s, rp, col, dinv, b2, h2, N);
    edge_probs<<<(E + 255) / 256, 256, 0, stream>>>(src, dst, h2, out, E);
}

// Round 6
// 331.331 us; speedup vs baseline: 3.0849x; 1.1755x over previous
//
#include <hip/hip_runtime.h>
#include <hip/hip_bf16.h>
#include <math.h>

#define F 128
#define NBLK 256      // blocks for bucket_count / bucket_scatter
#define MAXNB 2048    // max buckets (N up to 131072 at 64 nodes/bucket)

typedef short bf16x8 __attribute__((ext_vector_type(8)));
typedef float f32x4 __attribute__((ext_vector_type(4)));
typedef float f32x2 __attribute__((ext_vector_type(2)));

__device__ __forceinline__ int rfl(int v) { return __builtin_amdgcn_readfirstlane(v); }
__device__ __forceinline__ unsigned short f2bf(float f) {
    __hip_bfloat16 h = __float2bfloat16(f);
    return *reinterpret_cast<unsigned short*>(&h);
}
__device__ __forceinline__ unsigned pack2(float lo, float hi) {
    return (unsigned)f2bf(lo) | ((unsigned)f2bf(hi) << 16);
}

// ---------------- CSR build via counting sort (zero global atomics) ----------------

// K1: per-(block,bucket) histogram. Block b owns contiguous edge chunk.
__global__ __launch_bounds__(256) void bucket_count(
    const int* __restrict__ dst, int E, int NB, int chunk, int* __restrict__ hist2)
{
    __shared__ int h[MAXNB];
    for (int j = threadIdx.x; j < NB; j += 256) h[j] = 0;
    __syncthreads();
    int b = blockIdx.x;
    int beg = b * chunk, end = min(E, beg + chunk);
    for (int e = beg + threadIdx.x; e < end; e += 256)
        atomicAdd(&h[dst[e] >> 6], 1);             // LDS atomic
    __syncthreads();
    for (int j = threadIdx.x; j < NB; j += 256) hist2[b * NB + j] = h[j];
}

// K2: bucket bases (col-space incl self-loops, pair-space) + per-(block,bucket) bases.
__global__ __launch_bounds__(1024) void bucket_scan(
    int* __restrict__ hist2, int NB, int N,
    int* __restrict__ colbase, int* __restrict__ pairbase)
{
    __shared__ int ct[MAXNB], pt[MAXNB];
    int t = threadIdx.x;
    for (int j = t; j < MAXNB; j += 1024) { ct[j] = 0; pt[j] = 0; }
    __syncthreads();
    for (int j = t; j < NB; j += 1024) {
        int tot = 0;
        for (int b = 0; b < NBLK; ++b) tot += hist2[b * NB + j];
        int n0 = j << 6;
        int nodes = (n0 + 64 <= N) ? 64 : (N - n0);
        pt[j] = tot;
        ct[j] = tot + nodes;
    }
    __syncthreads();
    // Hillis-Steele inclusive scan over MAXNB, both arrays
    for (int off = 1; off < MAXNB; off <<= 1) {
        int i0 = t, i1 = t + 1024;
        int a0 = (i0 >= off) ? ct[i0 - off] : 0;
        int b0 = (i0 >= off) ? pt[i0 - off] : 0;
        int a1 = ct[i1 - off];
        int b1 = pt[i1 - off];
        __syncthreads();
        ct[i0] += a0; pt[i0] += b0;
        ct[i1] += a1; pt[i1] += b1;
        __syncthreads();
    }
    for (int j = t; j < NB; j += 1024) {
        colbase[j]  = j ? ct[j - 1] : 0;
        pairbase[j] = j ? pt[j - 1] : 0;
    }
    if (t == 0) { colbase[NB] = ct[NB - 1]; pairbase[NB] = pt[NB - 1]; }
    __syncthreads();
    // in-place: hist2[b][j] -> running base for block b within bucket j
    for (int j = t; j < NB; j += 1024) {
        int run = j ? pt[j - 1] : 0;
        for (int b = 0; b < NBLK; ++b) {
            int c = hist2[b * NB + j];
            hist2[b * NB + j] = run;
            run += c;
        }
    }
}

// K3: scatter (src,dst) into bucket regions; ranks via LDS atomics only.
__global__ __launch_bounds__(256) void bucket_scatter(
    const int* __restrict__ src, const int* __restrict__ dst, int E, int NB, int chunk,
    const int* __restrict__ gbase2, uint2* __restrict__ pairs)
{
    __shared__ int ofs[MAXNB];
    int b = blockIdx.x;
    for (int j = threadIdx.x; j < NB; j += 256) ofs[j] = gbase2[b * NB + j];
    __syncthreads();
    int beg = b * chunk, end = min(E, beg + chunk);
    for (int e = beg + threadIdx.x; e < end; e += 256) {
        int s = src[e], d = dst[e];
        int slot = atomicAdd(&ofs[d >> 6], 1);     // LDS atomic
        pairs[slot] = make_uint2((unsigned)s, (unsigned)d);
    }
}

// K4: per-bucket node-CSR: rp, dinv, self-loop, col scatter (bucket window ~8KB, L2).
__global__ __launch_bounds__(256) void bucket_csr(
    const uint2* __restrict__ pairs, const int* __restrict__ pairbase,
    const int* __restrict__ colbase, int N, int E,
    int* __restrict__ rp, int* __restrict__ col, float* __restrict__ dinv)
{
    __shared__ int cnt[64], fill[64], seg[64];
    int j = blockIdx.x;
    int t = threadIdx.x;
    if (t < 64) { cnt[t] = 0; fill[t] = 0; }
    __syncthreads();
    int beg = pairbase[j], end = pairbase[j + 1];
    int n0 = j << 6;
    for (int e = beg + t; e < end; e += 256)
        atomicAdd(&cnt[pairs[e].y & 63], 1);
    __syncthreads();
    if (t < 64) {
        int c = cnt[t];
        int v = c + 1;                 // + self-loop
#pragma unroll
        for (int off = 1; off < 64; off <<= 1) {
            int u = __shfl_up(v, off);
            if (t >= off) v += u;
        }
        int segb = colbase[j] + v - (c + 1);   // exclusive scan base
        int n = n0 + t;
        if (n < N) {
            seg[t] = segb;
            rp[n] = segb;
            dinv[n] = rsqrtf((float)(c + 1));
            col[segb + c] = n;                 // self-loop at segment end
            if (n == N - 1) rp[N] = segb + c + 1;
        }
    }
    __syncthreads();
    for (int e = beg + t; e < end; e += 256) {
        uint2 pr = pairs[e];
        int ln = (int)(pr.y & 63);
        int r = atomicAdd(&fill[ln], 1);       // LDS atomic
        col[seg[ln] + r] = (int)pr.x;
    }
}

// ------- W1 -> bf16, transposed [j][k], XOR-swizzled bytes (once) -------
__global__ void w1prep(const float* __restrict__ W1, unsigned char* __restrict__ W1t) {
    int tid = blockIdx.x * blockDim.x + threadIdx.x;   // tid = j*128 + k
    if (tid >= F * F) return;
    int j = tid >> 7, k = tid & 127;
    unsigned short w = f2bf(W1[k * F + j]);
    int ofs = (j << 8) + (((k << 1)) ^ ((j & 7) << 4));
    *reinterpret_cast<unsigned short*>(W1t + ofs) = w;
}

// ------- prescale: xsq[p][n][32] = fp8(dinv[n]*x[n][32p..32p+31]) -------
__global__ void prescale(const float* __restrict__ x, const float* __restrict__ dinv,
                         unsigned char* __restrict__ xsq, int N) {
    int i = blockIdx.x * blockDim.x + threadIdx.x;   // float4 group: n*32+g
    if (i >= N * 32) return;
    int n = i >> 5, g = i & 31;
    int p = g >> 3, q = g & 7;
    float d = dinv[n];
    float4 v = ((const float4*)x)[i];
    int r = __builtin_amdgcn_cvt_pk_fp8_f32(v.x * d, v.y * d, 0, false);
    r = __builtin_amdgcn_cvt_pk_fp8_f32(v.z * d, v.w * d, r, true);
    *reinterpret_cast<unsigned*>(xsq + (size_t)p * N * 32 + (size_t)n * 32 + 4 * q) = r;
}

// ------- aggregation pass: xa[n][32p..] = dinv_n * sum_s fp8row(s) -------
__global__ __launch_bounds__(256) void agg1(
    const unsigned char* __restrict__ xsq, const int* __restrict__ rp,
    const int* __restrict__ col, const float* __restrict__ dinv,
    unsigned short* __restrict__ xa, int N, int nbp)
{
    int p = blockIdx.x / nbp;
    int blk = blockIdx.x - p * nbp;
    int wave = threadIdx.x >> 6, lane = threadIdx.x & 63;
    int o = lane >> 3, c8 = lane & 7;
    int node0 = blk * 16 + wave * 4;
    if (node0 >= N) return;
    const unsigned char* xsp = xsq + (size_t)p * N * 32;

    int bg[4], dg[4];
    float dv[4];
    int maxdeg = 0;
#pragma unroll
    for (int n = 0; n < 4; ++n) {
        int i = node0 + n;
        int b = (i < N) ? rp[i] : 0;
        int e2 = (i < N) ? rp[i + 1] : 0;
        bg[n] = rfl(b);
        dg[n] = rfl(e2 - b);
        dv[n] = (i < N) ? dinv[i] : 0.f;
        maxdeg = maxdeg > dg[n] ? maxdeg : dg[n];
    }

    f32x2 acc[4][2] = {};
    for (int base = 0; base < maxdeg; base += 64) {
        int colv[4];
#pragma unroll
        for (int n = 0; n < 4; ++n)
            colv[n] = (base + lane < dg[n]) ? col[bg[n] + base + lane] : 0;
        int cm = maxdeg - base; if (cm > 64) cm = 64;
        int tm = (cm + 7) >> 3;
        for (int t = 0; t < tm; ++t) {
            int k = (t << 3) + o;
#pragma unroll
            for (int n = 0; n < 4; ++n) {
                if (base + k < dg[n]) {
                    int s = __shfl(colv[n], k);
                    unsigned u = *reinterpret_cast<const unsigned*>(xsp + (size_t)s * 32 + 4 * c8);
                    acc[n][0] += __builtin_amdgcn_cvt_pk_f32_fp8(u, false);
                    acc[n][1] += __builtin_amdgcn_cvt_pk_f32_fp8(u, true);
                }
            }
        }
    }

    float red[4][4];
#pragma unroll
    for (int n = 0; n < 4; ++n) {
        red[n][0] = acc[n][0].x; red[n][1] = acc[n][0].y;
        red[n][2] = acc[n][1].x; red[n][3] = acc[n][1].y;
#pragma unroll
        for (int j = 0; j < 4; ++j) {
            red[n][j] += __shfl_xor(red[n][j], 8);
            red[n][j] += __shfl_xor(red[n][j], 16);
            red[n][j] += __shfl_xor(red[n][j], 32);
        }
    }

    if (o < 4) {
        int i = node0 + o;
        if (i < N) {
            float d = dv[o];
            unsigned lo = pack2(red[o][0] * d, red[o][1] * d);
            unsigned hi = pack2(red[o][2] * d, red[o][3] * d);
            *reinterpret_cast<uint2*>(xa + (size_t)i * F + p * 32 + 4 * c8) =
                make_uint2(lo, hi);
        }
    }
}

// ------- MLP: h2s[i] = dinv_i * (relu(xa@W1 + b1) @ W2) via MFMA -------
__global__ __launch_bounds__(512) void mlp(
    const unsigned short* __restrict__ xa, const float* __restrict__ dinv,
    const float* __restrict__ b1, const float* __restrict__ W2,
    const unsigned char* __restrict__ W1t_g, float* __restrict__ h2s, int N)
{
    __shared__ unsigned char W1t[F * F * 2];   // 32 KB swizzled [j][k]
    __shared__ unsigned char XA[32 * 256];     // 8 KB swizzled [node][k]
    __shared__ float part[2][16][4];

    for (int idx = threadIdx.x; idx < (F * F * 2) / 16; idx += 512)
        ((int4*)W1t)[idx] = ((const int4*)W1t_g)[idx];

    {
        int r = threadIdx.x >> 4, t16 = threadIdx.x & 15;
        int gi = blockIdx.x * 32 + r;
        uint4 v = make_uint4(0, 0, 0, 0);
        if (gi < N) v = *reinterpret_cast<const uint4*>(xa + (size_t)gi * F + 8 * t16);
        *reinterpret_cast<uint4*>(XA + r * 256 + ((16 * t16) ^ ((r & 7) << 4))) = v;
    }
    __syncthreads();

    int wave = threadIdx.x >> 6, lane = threadIdx.x & 63;
    int g = wave >> 2, jt0 = (wave & 3) * 2;
    int l15 = lane & 15;
    int kb = (lane >> 4) * 16;

    bf16x8 afr[4];
    int arow = g * 16 + l15;
#pragma unroll
    for (int kk = 0; kk < 4; ++kk) {
        int ofs = arow * 256 + ((kk * 64 + kb) ^ ((arow & 7) << 4));
        afr[kk] = *reinterpret_cast<const bf16x8*>(XA + ofs);
    }

    float p[4] = {0.f, 0.f, 0.f, 0.f};
#pragma unroll
    for (int jj = 0; jj < 2; ++jj) {
        int j = (jt0 + jj) * 16 + l15;
        f32x4 d = {0.f, 0.f, 0.f, 0.f};
#pragma unroll
        for (int kk = 0; kk < 4; ++kk) {
            int ofs = j * 256 + ((kk * 64 + kb) ^ ((j & 7) << 4));
            bf16x8 bfr = *reinterpret_cast<const bf16x8*>(W1t + ofs);
            d = __builtin_amdgcn_mfma_f32_16x16x32_bf16(afr[kk], bfr, d, 0, 0, 0);
        }
        float bj = b1[j], wj = W2[j];
#pragma unroll
        for (int r = 0; r < 4; ++r) {
            float v = fmaxf(d[r] + bj, 0.f);
            p[r] += v * wj;
        }
    }
#pragma unroll
    for (int r = 0; r < 4; ++r) {
        p[r] += __shfl_xor(p[r], 1);
        p[r] += __shfl_xor(p[r], 2);
        p[r] += __shfl_xor(p[r], 4);
        p[r] += __shfl_xor(p[r], 8);
    }
    if (l15 == 0) {
#pragma unroll
        for (int r = 0; r < 4; ++r)
            part[g][(lane >> 4) * 4 + r][wave & 3] = p[r];
    }
    __syncthreads();

    if (threadIdx.x < 32) {
        int i = blockIdx.x * 32 + threadIdx.x;
        if (i < N) {
            const float* q = part[threadIdx.x >> 4][threadIdx.x & 15];
            h2s[i] = dinv[i] * (q[0] + q[1] + q[2] + q[3]);
        }
    }
}

// ------- layer 2 aggregation: quarter-wave (16 lanes) per node -------
__global__ __launch_bounds__(256) void agg2(
    const float* __restrict__ h2s, const int* __restrict__ rp,
    const int* __restrict__ col, const float* __restrict__ dinv,
    const float* __restrict__ b2, float* __restrict__ h2, int N)
{
    int nid = (blockIdx.x * 256 + threadIdx.x) >> 4;
    int c = threadIdx.x & 15;
    if (nid >= N) return;
    int beg = rfl(rp[nid]);
    int end = rfl(rp[nid + 1]);
    float s = 0.f;
    for (int e = beg + c; e < end; e += 16)
        s += h2s[col[e]];
#pragma unroll
    for (int off = 8; off; off >>= 1) s += __shfl_xor(s, off);
    if (c == 0) h2[nid] = dinv[nid] * s + b2[0];
}

// ------- edge probabilities -------
__global__ void edge_probs(const int* __restrict__ src, const int* __restrict__ dst,
                           const float* __restrict__ h2, float* __restrict__ out, int E) {
    int e = blockIdx.x * blockDim.x + threadIdx.x;
    if (e >= E) return;
    float v = h2[src[e]] * h2[dst[e]];
    out[e] = 1.0f / (1.0f + __expf(-v));
}

// ---------------- launch ----------------

extern "C" void kernel_launch(void* const* d_in, const int* in_sizes, int n_in,
                              void* d_out, int out_size, void* d_ws, size_t ws_size,
                              hipStream_t stream) {
    const float* x  = (const float*)d_in[0];
    const int*   ei = (const int*)d_in[1];       // int32 (JAX x64 disabled)
    const float* W1 = (const float*)d_in[2];
    const float* b1 = (const float*)d_in[3];
    const float* W2 = (const float*)d_in[4];
    const float* b2 = (const float*)d_in[5];
    float* out = (float*)d_out;

    int N = in_sizes[0] / F;
    int E = in_sizes[1] / 2;
    const int* src = ei;
    const int* dst = ei + E;
    int total = E + N;
    int NB = (N + 63) >> 6;                      // buckets of 64 nodes
    int chunk = (E + NBLK - 1) / NBLK;

    // workspace (~67 MB); pairs and xsq share one region (pairs dead after bucket_csr)
    char* ws = (char*)d_ws;
    size_t off = 0;
    auto alloc = [&](size_t bytes) -> void* {
        off = (off + 255) & ~(size_t)255;
        void* p = ws + off;
        off += bytes;
        return p;
    };
    float* dinv  = (float*)alloc((size_t)N * 4);
    int*   rp    = (int*)alloc((size_t)(N + 1) * 4);
    int*   hist2 = (int*)alloc((size_t)NBLK * NB * 4);
    int*   colbase  = (int*)alloc((size_t)(NB + 1) * 4);
    int*   pairbase = (int*)alloc((size_t)(NB + 1) * 4);
    int*   col   = (int*)alloc((size_t)total * 4);
    unsigned char* W1tg = (unsigned char*)alloc(F * F * 2);
    unsigned short* xa  = (unsigned short*)alloc((size_t)N * F * 2);
    float* h2s   = (float*)alloc((size_t)N * 4);
    float* h2    = (float*)alloc((size_t)N * 4);
    size_t uniBytes = (size_t)E * 8;             // pairs
    size_t xsqBytes = (size_t)N * 32 * 4;
    if (xsqBytes > uniBytes) uniBytes = xsqBytes;
    void* uni = alloc(uniBytes);
    uint2* pairs = (uint2*)uni;
    unsigned char* xsq = (unsigned char*)uni;
    (void)ws_size;

    int nbp = (N + 15) / 16;                     // agg1 blocks per pass

    bucket_count<<<NBLK, 256, 0, stream>>>(dst, E, NB, chunk, hist2);
    bucket_scan<<<1, 1024, 0, stream>>>(hist2, NB, N, colbase, pairbase);
    bucket_scatter<<<NBLK, 256, 0, stream>>>(src, dst, E, NB, chunk, hist2, pairs);
    bucket_csr<<<NB, 256, 0, stream>>>(pairs, pairbase, colbase, N, E, rp, col, dinv);
    w1prep<<<(F * F + 255) / 256, 256, 0, stream>>>(W1, W1tg);
    prescale<<<(N * 32 + 255) / 256, 256, 0, stream>>>(x, dinv, xsq, N);
    agg1<<<4 * nbp, 256, 0, stream>>>(xsq, rp, col, dinv, xa, N, nbp);
    mlp<<<(N + 31) / 32, 512, 0, stream>>>(xa, dinv, b1, W2, W1tg, h2s, N);
    agg2<<<((size_t)N * 16 + 255) / 256, 256, 0, stream>>>(h2s, rp, col, dinv, b2, h2, N);
    edge_probs<<<(E + 255) / 256, 256, 0, stream>>>(src, dst, h2, out, E);
}